// Round 13
// baseline (400.425 us; speedup 1.0000x reference)
//
#include <hip/hip_runtime.h>

// Problem constants (fixed by reference)
#define B_ROWS 8192
#define E_DIM  256
#define H_DIM  4096

typedef __attribute__((ext_vector_type(8))) short short8;
typedef __attribute__((ext_vector_type(4))) float f32x4;

typedef __attribute__((address_space(1))) const void* gas1_t;
typedef __attribute__((address_space(3))) void*       las3_t;

__device__ __forceinline__ float b2f(unsigned short s) {
    return __uint_as_float(((unsigned)s) << 16);
}
__device__ __forceinline__ unsigned short f2b(float f) {
    unsigned u = __float_as_uint(f);
    u += 0x7fffu + ((u >> 16) & 1u);   // RNE
    return (unsigned short)(u >> 16);
}

// HW packed f32->bf16 convert (1 instr for 2 elems vs 4 VALU ops each).
// GEMM2 A-path only; absmax bit-identical (7.63e-6) across R16-R27.
__device__ __forceinline__ unsigned cvt_pk_bf16(float lo, float hi) {
    unsigned r;
    asm("v_cvt_pk_bf16_f32 %0, %1, %2" : "=v"(r) : "v"(lo), "v"(hi));
    return r;
}

// LDS-only barrier: waits lgkmcnt(0) but does NOT drain vmcnt -- prefetched
// global loads stay in flight across the barrier (R21, proven). One barrier
// per iter suffices with double-buffering: each wave's iter-i ds_reads are
// lgkm-counted at the iter-(i+1) barrier, before buffer i&1 is rewritten.
__device__ __forceinline__ void lds_barrier() {
    asm volatile("s_waitcnt lgkmcnt(0)\n\ts_barrier" ::: "memory");
}

// LDS swizzle for BK=32 (64B rows, 4x16B slots): slot' = slot ^ ((row>>1)&3)
__device__ __forceinline__ int swz(int row, int slot) {
    return slot ^ ((row >> 1) & 3);
}

// ---------------------------------------------------------------------------
// Fused transpose+cast for BOTH weights in one launch (correctness-proven R23).
// blocks 0..1023: W1 [E,H] -> W1T; blocks 1024..2047: W2 [H,E] -> W2T.
__global__ void k_transpose_cast2(const float* __restrict__ W1,
                                  unsigned short* __restrict__ W1T,
                                  const float* __restrict__ W2,
                                  unsigned short* __restrict__ W2T) {
    const int bid = blockIdx.x;
    const int m = bid >> 10, b = bid & 1023;
    const float* in; unsigned short* out; int R, C, cx, cy;
    if (m == 0) { in = W1; out = W1T; R = E_DIM; C = H_DIM; cx = b & 127; cy = b >> 7; }
    else        { in = W2; out = W2T; R = H_DIM; C = E_DIM; cx = b & 7;   cy = b >> 3; }
    const int c0 = cx * 32, r0 = cy * 32;

    __shared__ float tile[32][33];
    const int tx = threadIdx.x & 31, ty = threadIdx.x >> 5;  // ty 0..7
#pragma unroll
    for (int j = 0; j < 4; ++j)
        tile[ty * 4 + j][tx] = in[(size_t)(r0 + ty * 4 + j) * C + c0 + tx];
    __syncthreads();
#pragma unroll
    for (int j = 0; j < 4; ++j)
        out[(size_t)(c0 + ty * 4 + j) * R + r0 + tx] = f2b(tile[tx][ty * 4 + j]);
}

// ---------------------------------------------------------------------------
// Cast f32 -> bf16 for BOTH views in one launch (correctness-proven R23).
__global__ void k_cast2(const float* __restrict__ z1, unsigned short* __restrict__ o1,
                        const float* __restrict__ z2, unsigned short* __restrict__ o2) {
    const float* in = blockIdx.y ? z2 : z1;
    unsigned short* out = blockIdx.y ? o2 : o1;
    int i = blockIdx.x * blockDim.x + threadIdx.x;
    float4 v = ((const float4*)in)[i];
    ushort4 o;
    o.x = f2b(v.x); o.y = f2b(v.y); o.z = f2b(v.z); o.w = f2b(v.w);
    ((ushort4*)out)[i] = o;
}

// ---------------------------------------------------------------------------
// GEMM1 (R28): exact gemm2d structure at BM=BN=128 -- register-staged,
// double-buffered, SINGLE lgkm-only barrier per iter (R27 had a redundant
// 2nd barrier that doubled segment count), BK=64 (R26's lever: halves
// segments again -> 4/block). 8-slot swizzle slot^(row&7), verified in
// gemm2d since R26. Each thread stages 4 A + 4 B uint4s (row=t>>3+32j,
// slot=t&7; (32j)&7==0 so swizzle offset is j-invariant). LDS 64KB ->
// 2 blocks/CU (= today's effective residency). Epilogue/stats unchanged.
__global__ __launch_bounds__(256) void k_gemm1(
    const unsigned short* __restrict__ A, const unsigned short* __restrict__ Bt,
    unsigned short* __restrict__ Cout,
    float* __restrict__ cs, float* __restrict__ cs2,
    int M, int N, int K) {
    constexpr int BK = 64, BM = 128, BN = 128;
    constexpr int MI = 4, NI = 4;
    __shared__ __align__(16) short As[2][BM * BK];   // 2 x 16 KB
    __shared__ __align__(16) short Bs[2][BN * BK];   // 2 x 16 KB

    const int t = threadIdx.x;
    const int lane = t & 63, wv = t >> 6;
    const int wr = wv >> 1, wc = wv & 1;
    const int l15 = lane & 15, quad = lane >> 4;
    const int m0 = blockIdx.y * BM, n0 = blockIdx.x * BN;

    const int ITERS = K / BK;   // 4

    // staging: row = t>>3 + 32j (j=0..3), slot = t&7 (8x16B slots/row)
    const int r0s = t >> 3, sl8 = t & 7;
    const unsigned short* ap = A + (size_t)(m0 + r0s) * K + sl8 * 8;
    const unsigned short* bp = Bt + (size_t)(n0 + r0s) * K + sl8 * 8;
    const int awo = r0s * BK + ((sl8 ^ (r0s & 7)) << 3);   // j-invariant swizzle

    f32x4 acc[MI][NI] = {};

    uint4 a[4], b[4];
#pragma unroll
    for (int j = 0; j < 4; ++j) {
        a[j] = *(const uint4*)(ap + (size_t)(32 * j) * K);
        b[j] = *(const uint4*)(bp + (size_t)(32 * j) * K);
    }

    for (int i = 0; i < ITERS; ++i) {
        short* Ab = As[i & 1];
        short* Bb = Bs[i & 1];

#pragma unroll
        for (int j = 0; j < 4; ++j) {
            *(uint4*)(Ab + awo + 32 * j * BK) = a[j];
            *(uint4*)(Bb + awo + 32 * j * BK) = b[j];
        }
        lds_barrier();   // lgkm-only: prefetch loads stay in flight

        const int kn = (i + 1 < ITERS) ? (i + 1) * BK : 0;
#pragma unroll
        for (int j = 0; j < 4; ++j) {
            a[j] = *(const uint4*)(ap + (size_t)(32 * j) * K + kn);
            b[j] = *(const uint4*)(bp + (size_t)(32 * j) * K + kn);
        }

#pragma unroll
        for (int kk = 0; kk < 2; ++kk) {
            short8 af[MI], bfr[NI];
#pragma unroll
            for (int mi = 0; mi < MI; ++mi) {
                int row = wr * 64 + mi * 16 + l15;
                af[mi] = *(const short8*)(Ab + row * BK + (((kk * 4 + quad) ^ (row & 7)) << 3));
            }
#pragma unroll
            for (int ni = 0; ni < NI; ++ni) {
                int row = wc * 64 + ni * 16 + l15;
                bfr[ni] = *(const short8*)(Bb + row * BK + (((kk * 4 + quad) ^ (row & 7)) << 3));
            }
#pragma unroll
            for (int mi = 0; mi < MI; ++mi)
#pragma unroll
                for (int ni = 0; ni < NI; ++ni)
                    acc[mi][ni] = __builtin_amdgcn_mfma_f32_16x16x32_bf16(
                        af[mi], bfr[ni], acc[mi][ni], 0, 0, 0);
        }
    }

    // epilogue: C/D layout col=lane&15, row=quad*4+reg (measured m89)
#pragma unroll
    for (int ni = 0; ni < NI; ++ni) {
        float s = 0.f, s2 = 0.f;
#pragma unroll
        for (int mi = 0; mi < MI; ++mi)
#pragma unroll
            for (int r = 0; r < 4; ++r) {
                int row = m0 + wr * 64 + mi * 16 + quad * 4 + r;
                int col = n0 + wc * 64 + ni * 16 + l15;
                float v = acc[mi][ni][r];
                Cout[(size_t)row * N + col] = f2b(v);
                s += v; s2 += v * v;
            }
        s  += __shfl_xor(s, 16);  s  += __shfl_xor(s, 32);
        s2 += __shfl_xor(s2, 16); s2 += __shfl_xor(s2, 32);
        if (quad == 0) {
            int col = n0 + wc * 64 + ni * 16 + l15;
            atomicAdd(&cs[col], s);
            atomicAdd(&cs2[col], s2);
        }
    }
}

// BN scale/shift packed as bf16 pair: ssb[k] = f2b(scale)<<16 | f2b(shift)
__global__ void k_bnprep(const float* __restrict__ sum, const float* __restrict__ sumsq,
                         const float* __restrict__ gamma, const float* __restrict__ beta,
                         unsigned* __restrict__ ssb) {
    int j = blockIdx.x * 256 + threadIdx.x;
    float mu = sum[j] * (1.f / B_ROWS);
    float var = sumsq[j] * (1.f / B_ROWS) - mu * mu;
    float sc = gamma[j] * rsqrtf(var + 1e-5f);
    float sh = beta[j] - mu * sc;
    ssb[j] = ((unsigned)f2b(sc) << 16) | (unsigned)f2b(sh);
}

__device__ __forceinline__ short8 bnrelu8(uint4 hv, uint4 sa, uint4 sb) {
    const unsigned short* hu = (const unsigned short*)&hv;
    const unsigned* wa = (const unsigned*)&sa;
    const unsigned* wb = (const unsigned*)&sb;
    float f[8];
#pragma unroll
    for (int j = 0; j < 8; ++j) {
        unsigned w = j < 4 ? wa[j] : wb[j - 4];
        float sc = __uint_as_float(w & 0xffff0000u);
        float sh = __uint_as_float(w << 16);
        f[j] = fmaxf(b2f(hu[j]) * sc + sh, 0.f);
    }
    union { unsigned u[4]; short8 s; } o;
#pragma unroll
    for (int j = 0; j < 4; ++j) o.u[j] = cvt_pk_bf16(f[2 * j], f[2 * j + 1]);
    return o.s;
}

// ---------------------------------------------------------------------------
// GEMM2 (R26, frozen): BK=64, XCD-pair swizzle, lgkm-only barrier, split-K x2.
__global__ __launch_bounds__(256, 4) void k_gemm2d(
    const unsigned short* __restrict__ A, const unsigned short* __restrict__ Bt,
    float* __restrict__ Cout, const float* __restrict__ bias,
    const unsigned* __restrict__ ssb,
    int M, int N, int K) {
    constexpr int BK = 64, BM = 32, BN = 128;
    constexpr int NI = 4;
    __shared__ __align__(16) short As[2][BM * BK];   // 2 x 4 KB
    __shared__ __align__(16) short Bs[2][BN * BK];   // 2 x 16 KB

    const int t = threadIdx.x;
    const int lane = t & 63, wv = t >> 6;
    const int wr = wv >> 1, wc = wv & 1;             // 2x2 wave grid, tile 16x64
    const int l15 = lane & 15, quad = lane >> 4;

    // XCD-pair swizzle decode (grid = 1024 x 1 x 1, split-K x2) -- R25 proven
    const int bid = blockIdx.x;
    const int xcd = bid & 7, sl = bid >> 3;
    const int xp = sl & 1, pidx = (sl >> 1) * 8 + xcd;   // 0..511
    const int m0 = (pidx & 255) * BM;                     // 256 m-blocks
    const int n0 = xp * BN;                               // 2 n-blocks
    const int bz = pidx >> 8;                             // 2 k-chunks

    const int Kc = K >> 1;                                // split-K x2
    const int kbeg = bz * Kc;
    const int ITERS = Kc / BK;                            // 32

    // A staging: all 256 threads, row = t>>3 (0..31), kslot = t&7 (8x16B/row)
    const int arow = t >> 3, aks = t & 7;
    const unsigned short* hp = A + (size_t)(m0 + arow) * K + aks * 8;
    const unsigned* ssp = ssb + aks * 8;
    const int aswz = (aks ^ (arow & 7)) << 3;             // (32j)&7==0 -> row-invariant
    const int awoff = arow * BK + aswz;

    // B staging: 4 row-chunks arow+32j at the same kslot
    const unsigned short* bp0 = Bt + (size_t)(n0 + arow) * K + aks * 8;
    const int bwoff0 = arow * BK + aswz;                  // + 32j*BK for j=1..3

    f32x4 acc[NI] = {};

    uint4 hreg = *(const uint4*)(hp + kbeg);
    uint4 sa = *(const uint4*)(ssp + kbeg);
    uint4 sb = *(const uint4*)(ssp + kbeg + 4);
    uint4 b0 = *(const uint4*)(bp0 + kbeg);
    uint4 b1 = *(const uint4*)(bp0 + (size_t)32 * K + kbeg);
    uint4 b2r = *(const uint4*)(bp0 + (size_t)64 * K + kbeg);
    uint4 b3 = *(const uint4*)(bp0 + (size_t)96 * K + kbeg);

    for (int i = 0; i < ITERS; ++i) {
        const int k0 = kbeg + i * BK;
        short* Ab = As[i & 1];
        short* Bb = Bs[i & 1];

        *(short8*)(Ab + awoff) = bnrelu8(hreg, sa, sb);
        *(uint4*)(Bb + bwoff0)           = b0;
        *(uint4*)(Bb + bwoff0 + 32 * BK) = b1;
        *(uint4*)(Bb + bwoff0 + 64 * BK) = b2r;
        *(uint4*)(Bb + bwoff0 + 96 * BK) = b3;
        lds_barrier();   // lgkm-only: prefetch loads stay in flight

        const int kn = (i + 1 < ITERS) ? k0 + BK : kbeg;
        hreg = *(const uint4*)(hp + kn);
        sa = *(const uint4*)(ssp + kn);
        sb = *(const uint4*)(ssp + kn + 4);
        b0 = *(const uint4*)(bp0 + kn);
        b1 = *(const uint4*)(bp0 + (size_t)32 * K + kn);
        b2r = *(const uint4*)(bp0 + (size_t)64 * K + kn);
        b3 = *(const uint4*)(bp0 + (size_t)96 * K + kn);

        // fragments: 2 k-halves (kk=0: slots quad; kk=1: slots 4+quad)
        short8 af[2], bfr[2][NI];
        {
            int row = wr * 16 + l15;
            af[0] = *(const short8*)(Ab + row * BK + (((quad)     ^ (row & 7)) << 3));
            af[1] = *(const short8*)(Ab + row * BK + (((4 + quad) ^ (row & 7)) << 3));
        }
#pragma unroll
        for (int ni = 0; ni < NI; ++ni) {
            int row = wc * 64 + ni * 16 + l15;
            bfr[0][ni] = *(const short8*)(Bb + row * BK + (((quad)     ^ (row & 7)) << 3));
            bfr[1][ni] = *(const short8*)(Bb + row * BK + (((4 + quad) ^ (row & 7)) << 3));
        }
#pragma unroll
        for (int kk = 0; kk < 2; ++kk)
#pragma unroll
            for (int ni = 0; ni < NI; ++ni)
                acc[ni] = __builtin_amdgcn_mfma_f32_16x16x32_bf16(
                    af[kk], bfr[kk][ni], acc[ni], 0, 0, 0);
    }

#pragma unroll
    for (int ni = 0; ni < NI; ++ni)
#pragma unroll
        for (int r = 0; r < 4; ++r) {
            int row = m0 + wr * 16 + quad * 4 + r;
            int col = n0 + wc * 64 + ni * 16 + l15;
            float v = acc[ni][r];
            if (bz == 0) v += bias[col];
            atomicAdd(&Cout[(size_t)row * N + col], v);
        }
}

// ---------------------------------------------------------------------------
// Fused norm + transpose + cast (R14-proven): grid (B/32, 4), block 256.
__global__ __launch_bounds__(256) void k_ntc(
    const float* __restrict__ x0, const float* __restrict__ x1,
    const float* __restrict__ x2, const float* __restrict__ x3,
    unsigned short* __restrict__ o0, unsigned short* __restrict__ o1,
    unsigned short* __restrict__ o2, unsigned short* __restrict__ o3) {
    const int z = blockIdx.y;
    const float* x = z == 0 ? x0 : z == 1 ? x1 : z == 2 ? x2 : x3;
    unsigned short* out = z == 0 ? o0 : z == 1 ? o1 : z == 2 ? o2 : o3;

    __shared__ float tile[32][264];
    __shared__ float red[32][8];
    __shared__ float invs[32];
    const int t = threadIdx.x;
    const int r0 = blockIdx.x * 32;

#pragma unroll
    for (int i = 0; i < 8; ++i) {
        int u = i * 256 + t;
        int row = u >> 6, cp = (u & 63) * 4;
        float4 v = *(const float4*)(x + (size_t)(r0 + row) * E_DIM + cp);
        *(float4*)&tile[row][cp] = v;
    }
    __syncthreads();
    {
        int row = t >> 3, cg = (t & 7) * 32;
        float s = 0.f;
#pragma unroll
        for (int j = 0; j < 32; ++j) { float v = tile[row][cg + j]; s += v * v; }
        red[row][t & 7] = s;
    }
    __syncthreads();
    if (t < 32) {
        float s = 0.f;
#pragma unroll
        for (int j = 0; j < 8; ++j) s += red[t][j];
        invs[t] = 1.f / fmaxf(sqrtf(s), 1e-12f);
    }
    __syncthreads();
    {
        int row = t & 31, cb = (t >> 5) * 32;
        float inv = invs[row];
#pragma unroll
        for (int j = 0; j < 32; ++j) {
            int c = cb + j;
            out[(size_t)c * B_ROWS + r0 + row] = f2b(tile[row][c] * inv);
        }
    }
}

// ---------------------------------------------------------------------------
// Gram via MFMA (R21 state): Mout[a,b] += sum_k AT[a,k]*BT[b,k].
// BM=BN=64, BK=32, swizzled staging, split-K x16; grid (4,4,32).
#define GKS 16
__global__ __launch_bounds__(256) void k_gram(
    const unsigned short* __restrict__ p1T, const unsigned short* __restrict__ q2T,
    const unsigned short* __restrict__ p2T, const unsigned short* __restrict__ q1T,
    float* __restrict__ Ma, float* __restrict__ Mb) {
    constexpr int BK = 32;
    const int mec = blockIdx.z >> 4, kz = blockIdx.z & 15;
    const unsigned short* A = mec ? p2T : p1T;
    const unsigned short* Bt = mec ? q1T : q2T;
    float* Mout = mec ? Mb : Ma;

    __shared__ __align__(16) short As[64 * BK];
    __shared__ __align__(16) short Bs[64 * BK];

    const int t = threadIdx.x;
    const int lane = t & 63, wv = t >> 6;
    const int wr = wv >> 1, wc = wv & 1;
    const int l15 = lane & 15, quad = lane >> 4;
    const int m0 = blockIdx.y * 64, n0 = blockIdx.x * 64;
    const int kbeg = kz * (B_ROWS / GKS);

    f32x4 acc[2][2] = {};

    for (int k0 = kbeg; k0 < kbeg + B_ROWS / GKS; k0 += BK) {
        {
            int row = t >> 2, kc = swz(row, t & 3);
            const short* gpa = (const short*)A + (size_t)(m0 + row) * B_ROWS + k0 + kc * 8;
            short* lpa = As + (size_t)(wv << 6) * 8;
            __builtin_amdgcn_global_load_lds((gas1_t)gpa, (las3_t)lpa, 16, 0, 0);
            const short* gpb = (const short*)Bt + (size_t)(n0 + row) * B_ROWS + k0 + kc * 8;
            short* lpb = Bs + (size_t)(wv << 6) * 8;
            __builtin_amdgcn_global_load_lds((gas1_t)gpb, (las3_t)lpb, 16, 0, 0);
        }
        __syncthreads();

        short8 af[2], bfr[2];
#pragma unroll
        for (int mi = 0; mi < 2; ++mi) {
            int row = wr * 32 + mi * 16 + l15;
            af[mi] = *(const short8*)(As + row * BK + (swz(row, quad) << 3));
        }
#pragma unroll
        for (int ni = 0; ni < 2; ++ni) {
            int row = wc * 32 + ni * 16 + l15;
            bfr[ni] = *(const short8*)(Bs + row * BK + (swz(row, quad) << 3));
        }
#pragma unroll
        for (int mi = 0; mi < 2; ++mi)
#pragma unroll
            for (int ni = 0; ni < 2; ++ni)
                acc[mi][ni] = __builtin_amdgcn_mfma_f32_16x16x32_bf16(
                    af[mi], bfr[ni], acc[mi][ni], 0, 0, 0);
        __syncthreads();
    }

#pragma unroll
    for (int mi = 0; mi < 2; ++mi)
#pragma unroll
        for (int ni = 0; ni < 2; ++ni)
#pragma unroll
            for (int r = 0; r < 4; ++r) {
                int row = m0 + wr * 32 + mi * 16 + quad * 4 + r;
                int col = n0 + wc * 32 + ni * 16 + l15;
                atomicAdd(&Mout[(size_t)row * E_DIM + col], acc[mi][ni][r]);
            }
}

// M2 = M*M (256x256). grid (16,16,2) block 256. (R21 state)
__global__ void k_m2(const float* __restrict__ Ma, const float* __restrict__ Mb,
                     float* __restrict__ M2a, float* __restrict__ M2b) {
    const float* M = blockIdx.z ? Mb : Ma;
    float* M2 = blockIdx.z ? M2b : M2a;
    int b = blockIdx.x * 16 + (threadIdx.x & 15);
    int a = blockIdx.y * 16 + (threadIdx.x >> 4);
    float s = 0.f;
    for (int k = 0; k < E_DIM; ++k) s += M[a * E_DIM + k] * M[k * E_DIM + b];
    M2[a * E_DIM + b] = s;
}

// ---------------------------------------------------------------------------
// Traces, tiled multi-block: grid (8,8,2), block 256.
__global__ __launch_bounds__(256) void k_traces2(
    const float* __restrict__ Ma, const float* __restrict__ M2a,
    const float* __restrict__ Mb, const float* __restrict__ M2b,
    const float* __restrict__ lam, float* __restrict__ out) {
    const float* M  = blockIdx.z ? Mb  : Ma;
    const float* M2 = blockIdx.z ? M2b : M2a;
    const int i0 = blockIdx.y * 32, j0 = blockIdx.x * 32;
    const int t = threadIdx.x, col = t & 31, row = t >> 5;  // row 0..7

    __shared__ float A[32][33], Bt[32][33], A2[32][33], B2[32][33];
#pragma unroll
    for (int r = 0; r < 4; ++r) {
        int rr = r * 8 + row;
        A [rr][col] = M [(i0 + rr) * E_DIM + j0 + col];
        Bt[rr][col] = M [(j0 + rr) * E_DIM + i0 + col];
        A2[rr][col] = M2[(i0 + rr) * E_DIM + j0 + col];
        B2[rr][col] = M2[(j0 + rr) * E_DIM + i0 + col];
    }
    __syncthreads();

    float lamv = lam[0];
    float il = 1.f / lamv;
    float F = -0.5f * lamv * (1.f / B_ROWS);  // -0.5*lam/B
    float c1 = F * il;
    float c2 = -F * 0.5f * il * il;
    float c3 = F * (1.f / 3.f) * il * il * il;
    float c4 = -F * 0.25f * il * il * il * il;

    float s = 0.f;
#pragma unroll
    for (int r = 0; r < 4; ++r) {
        int rr = r * 8 + row;
        float mij = A[rr][col], mji = Bt[col][rr];
        float m2ij = A2[rr][col], m2ji = B2[col][rr];
        s += c2 * mij * mji + c3 * m2ij * mji + c4 * m2ij * m2ji;
        if (i0 + rr == j0 + col) s += c1 * mij;
    }
#pragma unroll
    for (int o = 32; o; o >>= 1) s += __shfl_down(s, o);
    __shared__ float red[4];
    if ((t & 63) == 0) red[t >> 6] = s;
    __syncthreads();
    if (t == 0) atomicAdd(out, red[0] + red[1] + red[2] + red[3]);
}

// ---------------------------------------------------------------------------
extern "C" void kernel_launch(void* const* d_in, const int* in_sizes, int n_in,
                              void* d_out, int out_size, void* d_ws, size_t ws_size,
                              hipStream_t stream) {
    const float* z1 = (const float*)d_in[0];
    const float* z2 = (const float*)d_in[1];
    const float* p1 = (const float*)d_in[2];
    const float* p2 = (const float*)d_in[3];
    const float* W1 = (const float*)d_in[4];
    const float* gamma = (const float*)d_in[5];
    const float* beta = (const float*)d_in[6];
    const float* W2 = (const float*)d_in[7];
    const float* b2 = (const float*)d_in[8];
    const float* lam = (const float*)d_in[9];
    float* out = (float*)d_out;
    char* ws = (char*)d_ws;

    // workspace layout (~93 MB)
    size_t off = 0;
    auto alloc = [&](size_t bytes) { size_t o = off; off += (bytes + 255) & ~(size_t)255; return o; };
    unsigned short* W1T = (unsigned short*)(ws + alloc((size_t)E_DIM * H_DIM * 2));  // [H,E] bf16
    unsigned short* W2T = (unsigned short*)(ws + alloc((size_t)H_DIM * E_DIM * 2));  // [E,H] bf16
    unsigned short* zb1 = (unsigned short*)(ws + alloc((size_t)B_ROWS * E_DIM * 2));
    unsigned short* zb2 = (unsigned short*)(ws + alloc((size_t)B_ROWS * E_DIM * 2));
    unsigned short* h   = (unsigned short*)(ws + alloc((size_t)B_ROWS * H_DIM * 2));
    // q1,q2,Ma,Mb contiguous -> single memset
    float* q1 = (float*)(ws + alloc((size_t)B_ROWS * E_DIM * 4));
    float* q2 = (float*)(ws + alloc((size_t)B_ROWS * E_DIM * 4));
    float* Ma  = (float*)(ws + alloc((size_t)E_DIM * E_DIM * 4));
    float* Mb  = (float*)(ws + alloc((size_t)E_DIM * E_DIM * 4));
    float* M2a = (float*)(ws + alloc((size_t)E_DIM * E_DIM * 4));
    float* M2b = (float*)(ws + alloc((size_t)E_DIM * E_DIM * 4));
    // two colsum sets (one per view), contiguous -> single memset
    float* cs0 = (float*)(ws + alloc(H_DIM * 4));
    float* cs0q = (float*)(ws + alloc(H_DIM * 4));
    float* cs1 = (float*)(ws + alloc(H_DIM * 4));
    float* cs1q = (float*)(ws + alloc(H_DIM * 4));
    unsigned* ssb = (unsigned*)(ws + alloc(H_DIM * 4));

    // transposed normalized bf16 views alias into h (free after last GEMM2)
    const size_t TSZ = (size_t)E_DIM * B_ROWS;  // 2M elements each
    unsigned short* p1T = h;
    unsigned short* q2T = h + TSZ;
    unsigned short* p2T = h + 2 * TSZ;
    unsigned short* q1T = h + 3 * TSZ;

    // zero accumulation targets (3 memsets total)
    hipMemsetAsync(out, 0, sizeof(float), stream);
    hipMemsetAsync(q1, 0, ((size_t)2 * B_ROWS * E_DIM + 2 * E_DIM * E_DIM) * 4, stream);
    hipMemsetAsync(cs0, 0, (size_t)4 * H_DIM * 4, stream);

    // fused weight transposes + fused view casts (-2 launches, proven R23)
    k_transpose_cast2<<<dim3(2048), 256, 0, stream>>>(W1, W1T, W2, W2T);
    k_cast2<<<dim3(B_ROWS * E_DIM / 4 / 256, 2), 256, 0, stream>>>(z1, zb1, z2, zb2);

    const unsigned short* zbs[2] = {zb1, zb2};
    float* qs[2] = {q1, q2};
    float* css[2] = {cs0, cs1};
    float* cssq[2] = {cs0q, cs1q};
    for (int v = 0; v < 2; ++v) {
        // h = z @ W1, with fused column stats — BK=64, single-barrier reg-staged
        k_gemm1<<<dim3(H_DIM / 128, B_ROWS / 128), 256, 0, stream>>>(
            zbs[v], W1T, h, css[v], cssq[v], B_ROWS, H_DIM, E_DIM);
        k_bnprep<<<dim3(H_DIM / 256), 256, 0, stream>>>(css[v], cssq[v], gamma, beta, ssb);
        // q = relu(bn(h)) @ W2 + b2 — BK=64, XCD-pair swizzle, split-K x2
        k_gemm2d<<<dim3(1024), 256, 0, stream>>>(
            h, W2T, qs[v], b2, ssb, B_ROWS, E_DIM, H_DIM);
    }

    // fused row-norm + transpose + cast of p1,q2,p2,q1 (into h's space)
    k_ntc<<<dim3(B_ROWS / 32, 4), 256, 0, stream>>>(
        p1, q2, p2, q1, p1T, q2T, p2T, q1T);

    k_gram<<<dim3(4, 4, 2 * GKS), 256, 0, stream>>>(p1T, q2T, p2T, q1T, Ma, Mb);
    k_m2<<<dim3(16, 16, 2), 256, 0, stream>>>(Ma, Mb, M2a, M2b);
    k_traces2<<<dim3(8, 8, 2), 256, 0, stream>>>(Ma, M2a, Mb, M2b, lam, out);
}

// Round 14
// 306.218 us; speedup vs baseline: 1.3076x; 1.3076x over previous
//
#include <hip/hip_runtime.h>

// Problem constants (fixed by reference)
#define B_ROWS 8192
#define E_DIM  256
#define H_DIM  4096

typedef __attribute__((ext_vector_type(8))) short short8;
typedef __attribute__((ext_vector_type(4))) float f32x4;

typedef __attribute__((address_space(1))) const void* gas1_t;
typedef __attribute__((address_space(3))) void*       las3_t;

__device__ __forceinline__ float b2f(unsigned short s) {
    return __uint_as_float(((unsigned)s) << 16);
}
__device__ __forceinline__ unsigned short f2b(float f) {
    unsigned u = __float_as_uint(f);
    u += 0x7fffu + ((u >> 16) & 1u);   // RNE
    return (unsigned short)(u >> 16);
}

// HW packed f32->bf16 convert (1 instr for 2 elems vs 4 VALU ops each).
// GEMM2 A-path only; absmax bit-identical (7.63e-6) across R16-R28.
__device__ __forceinline__ unsigned cvt_pk_bf16(float lo, float hi) {
    unsigned r;
    asm("v_cvt_pk_bf16_f32 %0, %1, %2" : "=v"(r) : "v"(lo), "v"(hi));
    return r;
}

// LDS-only barrier: waits lgkmcnt(0) but does NOT drain vmcnt -- prefetched
// global loads stay in flight across the barrier (R21, proven). ONE barrier
// per iter suffices with double-buffering: each wave's iter-i ds_reads are
// lgkm-counted at the iter-(i+1) barrier, before buffer i&1 is rewritten
// at iter i+2 (gemm2d has run this protocol since R21).
__device__ __forceinline__ void lds_barrier() {
    asm volatile("s_waitcnt lgkmcnt(0)\n\ts_barrier" ::: "memory");
}

// LDS swizzle for BK=32 (64B rows, 4x16B slots): slot' = slot ^ ((row>>1)&3)
__device__ __forceinline__ int swz(int row, int slot) {
    return slot ^ ((row >> 1) & 3);
}

// ---------------------------------------------------------------------------
// Fused transpose+cast for BOTH weights in one launch (correctness-proven R23).
// blocks 0..1023: W1 [E,H] -> W1T; blocks 1024..2047: W2 [H,E] -> W2T.
__global__ void k_transpose_cast2(const float* __restrict__ W1,
                                  unsigned short* __restrict__ W1T,
                                  const float* __restrict__ W2,
                                  unsigned short* __restrict__ W2T) {
    const int bid = blockIdx.x;
    const int m = bid >> 10, b = bid & 1023;
    const float* in; unsigned short* out; int R, C, cx, cy;
    if (m == 0) { in = W1; out = W1T; R = E_DIM; C = H_DIM; cx = b & 127; cy = b >> 7; }
    else        { in = W2; out = W2T; R = H_DIM; C = E_DIM; cx = b & 7;   cy = b >> 3; }
    const int c0 = cx * 32, r0 = cy * 32;

    __shared__ float tile[32][33];
    const int tx = threadIdx.x & 31, ty = threadIdx.x >> 5;  // ty 0..7
#pragma unroll
    for (int j = 0; j < 4; ++j)
        tile[ty * 4 + j][tx] = in[(size_t)(r0 + ty * 4 + j) * C + c0 + tx];
    __syncthreads();
#pragma unroll
    for (int j = 0; j < 4; ++j)
        out[(size_t)(c0 + ty * 4 + j) * R + r0 + tx] = f2b(tile[tx][ty * 4 + j]);
}

// ---------------------------------------------------------------------------
// Cast f32 -> bf16 for BOTH views in one launch (correctness-proven R23).
__global__ void k_cast2(const float* __restrict__ z1, unsigned short* __restrict__ o1,
                        const float* __restrict__ z2, unsigned short* __restrict__ o2) {
    const float* in = blockIdx.y ? z2 : z1;
    unsigned short* out = blockIdx.y ? o2 : o1;
    int i = blockIdx.x * blockDim.x + threadIdx.x;
    float4 v = ((const float4*)in)[i];
    ushort4 o;
    o.x = f2b(v.x); o.y = f2b(v.y); o.z = f2b(v.z); o.w = f2b(v.w);
    ((ushort4*)out)[i] = o;
}

// ---------------------------------------------------------------------------
// GEMM1 (R29 = R27 minus its one flaw): register-staged, double-buffered,
// BK=32, proven swizzle, SINGLE lgkm-only barrier per iter (R27 had a
// redundant 2nd barrier; R28's BK=64 variant blew LDS to 80KB + 5.5M bank
// conflicts -- reverted). LDS 32KB -> ~5 blocks/CU. Epilogue/stats unchanged.
__global__ __launch_bounds__(256) void k_gemm1(
    const unsigned short* __restrict__ A, const unsigned short* __restrict__ Bt,
    unsigned short* __restrict__ Cout,
    float* __restrict__ cs, float* __restrict__ cs2,
    int M, int N, int K) {
    constexpr int BK = 32, BM = 128, BN = 128;
    constexpr int MI = 4, NI = 4;
    __shared__ __align__(16) short As[2][BM * BK];   // 2 x 8 KB
    __shared__ __align__(16) short Bs[2][BN * BK];   // 2 x 8 KB

    const int t = threadIdx.x;
    const int lane = t & 63, wv = t >> 6;
    const int wr = wv >> 1, wc = wv & 1;
    const int l15 = lane & 15, quad = lane >> 4;
    const int m0 = blockIdx.y * BM, n0 = blockIdx.x * BN;

    const int ITERS = K / BK;   // 8

    // staging: unit u in {t, t+256}: row = u>>2 (0..127), slot = u&3
    const int r0s = t >> 2, sl = t & 3;
    const unsigned short* ap0 = A + (size_t)(m0 + r0s) * K + sl * 8;
    const unsigned short* ap1 = A + (size_t)(m0 + 64 + r0s) * K + sl * 8;
    const unsigned short* bp0 = Bt + (size_t)(n0 + r0s) * K + sl * 8;
    const unsigned short* bp1 = Bt + (size_t)(n0 + 64 + r0s) * K + sl * 8;
    const int awo0 = r0s * BK + (swz(r0s, sl) << 3);
    const int awo1 = (64 + r0s) * BK + (swz(64 + r0s, sl) << 3);

    f32x4 acc[MI][NI] = {};

    uint4 a0 = *(const uint4*)(ap0);
    uint4 a1 = *(const uint4*)(ap1);
    uint4 b0 = *(const uint4*)(bp0);
    uint4 b1 = *(const uint4*)(bp1);

    for (int i = 0; i < ITERS; ++i) {
        short* Ab = As[i & 1];
        short* Bb = Bs[i & 1];

        *(uint4*)(Ab + awo0) = a0;
        *(uint4*)(Ab + awo1) = a1;
        *(uint4*)(Bb + awo0) = b0;   // B uses same row/slot layout as A
        *(uint4*)(Bb + awo1) = b1;
        lds_barrier();   // the ONLY barrier per iter (single-barrier protocol)

        const int kn = (i + 1 < ITERS) ? (i + 1) * BK : 0;
        a0 = *(const uint4*)(ap0 + kn);
        a1 = *(const uint4*)(ap1 + kn);
        b0 = *(const uint4*)(bp0 + kn);
        b1 = *(const uint4*)(bp1 + kn);

        short8 af[MI], bfr[NI];
#pragma unroll
        for (int mi = 0; mi < MI; ++mi) {
            int row = wr * 64 + mi * 16 + l15;
            af[mi] = *(const short8*)(Ab + row * BK + (swz(row, quad) << 3));
        }
#pragma unroll
        for (int ni = 0; ni < NI; ++ni) {
            int row = wc * 64 + ni * 16 + l15;
            bfr[ni] = *(const short8*)(Bb + row * BK + (swz(row, quad) << 3));
        }
#pragma unroll
        for (int mi = 0; mi < MI; ++mi)
#pragma unroll
            for (int ni = 0; ni < NI; ++ni)
                acc[mi][ni] = __builtin_amdgcn_mfma_f32_16x16x32_bf16(
                    af[mi], bfr[ni], acc[mi][ni], 0, 0, 0);
    }

    // epilogue: C/D layout col=lane&15, row=quad*4+reg (measured m89)
#pragma unroll
    for (int ni = 0; ni < NI; ++ni) {
        float s = 0.f, s2 = 0.f;
#pragma unroll
        for (int mi = 0; mi < MI; ++mi)
#pragma unroll
            for (int r = 0; r < 4; ++r) {
                int row = m0 + wr * 64 + mi * 16 + quad * 4 + r;
                int col = n0 + wc * 64 + ni * 16 + l15;
                float v = acc[mi][ni][r];
                Cout[(size_t)row * N + col] = f2b(v);
                s += v; s2 += v * v;
            }
        s  += __shfl_xor(s, 16);  s  += __shfl_xor(s, 32);
        s2 += __shfl_xor(s2, 16); s2 += __shfl_xor(s2, 32);
        if (quad == 0) {
            int col = n0 + wc * 64 + ni * 16 + l15;
            atomicAdd(&cs[col], s);
            atomicAdd(&cs2[col], s2);
        }
    }
}

// BN scale/shift packed as bf16 pair: ssb[k] = f2b(scale)<<16 | f2b(shift)
__global__ void k_bnprep(const float* __restrict__ sum, const float* __restrict__ sumsq,
                         const float* __restrict__ gamma, const float* __restrict__ beta,
                         unsigned* __restrict__ ssb) {
    int j = blockIdx.x * 256 + threadIdx.x;
    float mu = sum[j] * (1.f / B_ROWS);
    float var = sumsq[j] * (1.f / B_ROWS) - mu * mu;
    float sc = gamma[j] * rsqrtf(var + 1e-5f);
    float sh = beta[j] - mu * sc;
    ssb[j] = ((unsigned)f2b(sc) << 16) | (unsigned)f2b(sh);
}

__device__ __forceinline__ short8 bnrelu8(uint4 hv, uint4 sa, uint4 sb) {
    const unsigned short* hu = (const unsigned short*)&hv;
    const unsigned* wa = (const unsigned*)&sa;
    const unsigned* wb = (const unsigned*)&sb;
    float f[8];
#pragma unroll
    for (int j = 0; j < 8; ++j) {
        unsigned w = j < 4 ? wa[j] : wb[j - 4];
        float sc = __uint_as_float(w & 0xffff0000u);
        float sh = __uint_as_float(w << 16);
        f[j] = fmaxf(b2f(hu[j]) * sc + sh, 0.f);
    }
    union { unsigned u[4]; short8 s; } o;
#pragma unroll
    for (int j = 0; j < 4; ++j) o.u[j] = cvt_pk_bf16(f[2 * j], f[2 * j + 1]);
    return o.s;
}

// ---------------------------------------------------------------------------
// GEMM2 (R26, frozen): BK=64, XCD-pair swizzle, lgkm-only barrier, split-K x2.
__global__ __launch_bounds__(256, 4) void k_gemm2d(
    const unsigned short* __restrict__ A, const unsigned short* __restrict__ Bt,
    float* __restrict__ Cout, const float* __restrict__ bias,
    const unsigned* __restrict__ ssb,
    int M, int N, int K) {
    constexpr int BK = 64, BM = 32, BN = 128;
    constexpr int NI = 4;
    __shared__ __align__(16) short As[2][BM * BK];   // 2 x 4 KB
    __shared__ __align__(16) short Bs[2][BN * BK];   // 2 x 16 KB

    const int t = threadIdx.x;
    const int lane = t & 63, wv = t >> 6;
    const int wr = wv >> 1, wc = wv & 1;             // 2x2 wave grid, tile 16x64
    const int l15 = lane & 15, quad = lane >> 4;

    // XCD-pair swizzle decode (grid = 1024 x 1 x 1, split-K x2) -- R25 proven
    const int bid = blockIdx.x;
    const int xcd = bid & 7, sl = bid >> 3;
    const int xp = sl & 1, pidx = (sl >> 1) * 8 + xcd;   // 0..511
    const int m0 = (pidx & 255) * BM;                     // 256 m-blocks
    const int n0 = xp * BN;                               // 2 n-blocks
    const int bz = pidx >> 8;                             // 2 k-chunks

    const int Kc = K >> 1;                                // split-K x2
    const int kbeg = bz * Kc;
    const int ITERS = Kc / BK;                            // 32

    // A staging: all 256 threads, row = t>>3 (0..31), kslot = t&7 (8x16B/row)
    const int arow = t >> 3, aks = t & 7;
    const unsigned short* hp = A + (size_t)(m0 + arow) * K + aks * 8;
    const unsigned* ssp = ssb + aks * 8;
    const int aswz = (aks ^ (arow & 7)) << 3;             // (32j)&7==0 -> row-invariant
    const int awoff = arow * BK + aswz;

    // B staging: 4 row-chunks arow+32j at the same kslot
    const unsigned short* bp0 = Bt + (size_t)(n0 + arow) * K + aks * 8;
    const int bwoff0 = arow * BK + aswz;                  // + 32j*BK for j=1..3

    f32x4 acc[NI] = {};

    uint4 hreg = *(const uint4*)(hp + kbeg);
    uint4 sa = *(const uint4*)(ssp + kbeg);
    uint4 sb = *(const uint4*)(ssp + kbeg + 4);
    uint4 b0 = *(const uint4*)(bp0 + kbeg);
    uint4 b1 = *(const uint4*)(bp0 + (size_t)32 * K + kbeg);
    uint4 b2r = *(const uint4*)(bp0 + (size_t)64 * K + kbeg);
    uint4 b3 = *(const uint4*)(bp0 + (size_t)96 * K + kbeg);

    for (int i = 0; i < ITERS; ++i) {
        const int k0 = kbeg + i * BK;
        short* Ab = As[i & 1];
        short* Bb = Bs[i & 1];

        *(short8*)(Ab + awoff) = bnrelu8(hreg, sa, sb);
        *(uint4*)(Bb + bwoff0)           = b0;
        *(uint4*)(Bb + bwoff0 + 32 * BK) = b1;
        *(uint4*)(Bb + bwoff0 + 64 * BK) = b2r;
        *(uint4*)(Bb + bwoff0 + 96 * BK) = b3;
        lds_barrier();   // lgkm-only: prefetch loads stay in flight

        const int kn = (i + 1 < ITERS) ? k0 + BK : kbeg;
        hreg = *(const uint4*)(hp + kn);
        sa = *(const uint4*)(ssp + kn);
        sb = *(const uint4*)(ssp + kn + 4);
        b0 = *(const uint4*)(bp0 + kn);
        b1 = *(const uint4*)(bp0 + (size_t)32 * K + kn);
        b2r = *(const uint4*)(bp0 + (size_t)64 * K + kn);
        b3 = *(const uint4*)(bp0 + (size_t)96 * K + kn);

        // fragments: 2 k-halves (kk=0: slots quad; kk=1: slots 4+quad)
        short8 af[2], bfr[2][NI];
        {
            int row = wr * 16 + l15;
            af[0] = *(const short8*)(Ab + row * BK + (((quad)     ^ (row & 7)) << 3));
            af[1] = *(const short8*)(Ab + row * BK + (((4 + quad) ^ (row & 7)) << 3));
        }
#pragma unroll
        for (int ni = 0; ni < NI; ++ni) {
            int row = wc * 64 + ni * 16 + l15;
            bfr[0][ni] = *(const short8*)(Bb + row * BK + (((quad)     ^ (row & 7)) << 3));
            bfr[1][ni] = *(const short8*)(Bb + row * BK + (((4 + quad) ^ (row & 7)) << 3));
        }
#pragma unroll
        for (int kk = 0; kk < 2; ++kk)
#pragma unroll
            for (int ni = 0; ni < NI; ++ni)
                acc[ni] = __builtin_amdgcn_mfma_f32_16x16x32_bf16(
                    af[kk], bfr[kk][ni], acc[ni], 0, 0, 0);
    }

#pragma unroll
    for (int ni = 0; ni < NI; ++ni)
#pragma unroll
        for (int r = 0; r < 4; ++r) {
            int row = m0 + wr * 16 + quad * 4 + r;
            int col = n0 + wc * 64 + ni * 16 + l15;
            float v = acc[ni][r];
            if (bz == 0) v += bias[col];
            atomicAdd(&Cout[(size_t)row * N + col], v);
        }
}

// ---------------------------------------------------------------------------
// Fused norm + transpose + cast (R14-proven): grid (B/32, 4), block 256.
__global__ __launch_bounds__(256) void k_ntc(
    const float* __restrict__ x0, const float* __restrict__ x1,
    const float* __restrict__ x2, const float* __restrict__ x3,
    unsigned short* __restrict__ o0, unsigned short* __restrict__ o1,
    unsigned short* __restrict__ o2, unsigned short* __restrict__ o3) {
    const int z = blockIdx.y;
    const float* x = z == 0 ? x0 : z == 1 ? x1 : z == 2 ? x2 : x3;
    unsigned short* out = z == 0 ? o0 : z == 1 ? o1 : z == 2 ? o2 : o3;

    __shared__ float tile[32][264];
    __shared__ float red[32][8];
    __shared__ float invs[32];
    const int t = threadIdx.x;
    const int r0 = blockIdx.x * 32;

#pragma unroll
    for (int i = 0; i < 8; ++i) {
        int u = i * 256 + t;
        int row = u >> 6, cp = (u & 63) * 4;
        float4 v = *(const float4*)(x + (size_t)(r0 + row) * E_DIM + cp);
        *(float4*)&tile[row][cp] = v;
    }
    __syncthreads();
    {
        int row = t >> 3, cg = (t & 7) * 32;
        float s = 0.f;
#pragma unroll
        for (int j = 0; j < 32; ++j) { float v = tile[row][cg + j]; s += v * v; }
        red[row][t & 7] = s;
    }
    __syncthreads();
    if (t < 32) {
        float s = 0.f;
#pragma unroll
        for (int j = 0; j < 8; ++j) s += red[t][j];
        invs[t] = 1.f / fmaxf(sqrtf(s), 1e-12f);
    }
    __syncthreads();
    {
        int row = t & 31, cb = (t >> 5) * 32;
        float inv = invs[row];
#pragma unroll
        for (int j = 0; j < 32; ++j) {
            int c = cb + j;
            out[(size_t)c * B_ROWS + r0 + row] = f2b(tile[row][c] * inv);
        }
    }
}

// ---------------------------------------------------------------------------
// Gram via MFMA (R21 state): Mout[a,b] += sum_k AT[a,k]*BT[b,k].
// BM=BN=64, BK=32, swizzled staging, split-K x16; grid (4,4,32).
#define GKS 16
__global__ __launch_bounds__(256) void k_gram(
    const unsigned short* __restrict__ p1T, const unsigned short* __restrict__ q2T,
    const unsigned short* __restrict__ p2T, const unsigned short* __restrict__ q1T,
    float* __restrict__ Ma, float* __restrict__ Mb) {
    constexpr int BK = 32;
    const int mec = blockIdx.z >> 4, kz = blockIdx.z & 15;
    const unsigned short* A = mec ? p2T : p1T;
    const unsigned short* Bt = mec ? q1T : q2T;
    float* Mout = mec ? Mb : Ma;

    __shared__ __align__(16) short As[64 * BK];
    __shared__ __align__(16) short Bs[64 * BK];

    const int t = threadIdx.x;
    const int lane = t & 63, wv = t >> 6;
    const int wr = wv >> 1, wc = wv & 1;
    const int l15 = lane & 15, quad = lane >> 4;
    const int m0 = blockIdx.y * 64, n0 = blockIdx.x * 64;
    const int kbeg = kz * (B_ROWS / GKS);

    f32x4 acc[2][2] = {};

    for (int k0 = kbeg; k0 < kbeg + B_ROWS / GKS; k0 += BK) {
        {
            int row = t >> 2, kc = swz(row, t & 3);
            const short* gpa = (const short*)A + (size_t)(m0 + row) * B_ROWS + k0 + kc * 8;
            short* lpa = As + (size_t)(wv << 6) * 8;
            __builtin_amdgcn_global_load_lds((gas1_t)gpa, (las3_t)lpa, 16, 0, 0);
            const short* gpb = (const short*)Bt + (size_t)(n0 + row) * B_ROWS + k0 + kc * 8;
            short* lpb = Bs + (size_t)(wv << 6) * 8;
            __builtin_amdgcn_global_load_lds((gas1_t)gpb, (las3_t)lpb, 16, 0, 0);
        }
        __syncthreads();

        short8 af[2], bfr[2];
#pragma unroll
        for (int mi = 0; mi < 2; ++mi) {
            int row = wr * 32 + mi * 16 + l15;
            af[mi] = *(const short8*)(As + row * BK + (swz(row, quad) << 3));
        }
#pragma unroll
        for (int ni = 0; ni < 2; ++ni) {
            int row = wc * 32 + ni * 16 + l15;
            bfr[ni] = *(const short8*)(Bs + row * BK + (swz(row, quad) << 3));
        }
#pragma unroll
        for (int mi = 0; mi < 2; ++mi)
#pragma unroll
            for (int ni = 0; ni < 2; ++ni)
                acc[mi][ni] = __builtin_amdgcn_mfma_f32_16x16x32_bf16(
                    af[mi], bfr[ni], acc[mi][ni], 0, 0, 0);
        __syncthreads();
    }

#pragma unroll
    for (int mi = 0; mi < 2; ++mi)
#pragma unroll
        for (int ni = 0; ni < 2; ++ni)
#pragma unroll
            for (int r = 0; r < 4; ++r) {
                int row = m0 + wr * 32 + mi * 16 + quad * 4 + r;
                int col = n0 + wc * 32 + ni * 16 + l15;
                atomicAdd(&Mout[(size_t)row * E_DIM + col], acc[mi][ni][r]);
            }
}

// M2 = M*M (256x256). grid (16,16,2) block 256. (R21 state)
__global__ void k_m2(const float* __restrict__ Ma, const float* __restrict__ Mb,
                     float* __restrict__ M2a, float* __restrict__ M2b) {
    const float* M = blockIdx.z ? Mb : Ma;
    float* M2 = blockIdx.z ? M2b : M2a;
    int b = blockIdx.x * 16 + (threadIdx.x & 15);
    int a = blockIdx.y * 16 + (threadIdx.x >> 4);
    float s = 0.f;
    for (int k = 0; k < E_DIM; ++k) s += M[a * E_DIM + k] * M[k * E_DIM + b];
    M2[a * E_DIM + b] = s;
}

// ---------------------------------------------------------------------------
// Traces, tiled multi-block: grid (8,8,2), block 256.
__global__ __launch_bounds__(256) void k_traces2(
    const float* __restrict__ Ma, const float* __restrict__ M2a,
    const float* __restrict__ Mb, const float* __restrict__ M2b,
    const float* __restrict__ lam, float* __restrict__ out) {
    const float* M  = blockIdx.z ? Mb  : Ma;
    const float* M2 = blockIdx.z ? M2b : M2a;
    const int i0 = blockIdx.y * 32, j0 = blockIdx.x * 32;
    const int t = threadIdx.x, col = t & 31, row = t >> 5;  // row 0..7

    __shared__ float A[32][33], Bt[32][33], A2[32][33], B2[32][33];
#pragma unroll
    for (int r = 0; r < 4; ++r) {
        int rr = r * 8 + row;
        A [rr][col] = M [(i0 + rr) * E_DIM + j0 + col];
        Bt[rr][col] = M [(j0 + rr) * E_DIM + i0 + col];
        A2[rr][col] = M2[(i0 + rr) * E_DIM + j0 + col];
        B2[rr][col] = M2[(j0 + rr) * E_DIM + i0 + col];
    }
    __syncthreads();

    float lamv = lam[0];
    float il = 1.f / lamv;
    float F = -0.5f * lamv * (1.f / B_ROWS);  // -0.5*lam/B
    float c1 = F * il;
    float c2 = -F * 0.5f * il * il;
    float c3 = F * (1.f / 3.f) * il * il * il;
    float c4 = -F * 0.25f * il * il * il * il;

    float s = 0.f;
#pragma unroll
    for (int r = 0; r < 4; ++r) {
        int rr = r * 8 + row;
        float mij = A[rr][col], mji = Bt[col][rr];
        float m2ij = A2[rr][col], m2ji = B2[col][rr];
        s += c2 * mij * mji + c3 * m2ij * mji + c4 * m2ij * m2ji;
        if (i0 + rr == j0 + col) s += c1 * mij;
    }
#pragma unroll
    for (int o = 32; o; o >>= 1) s += __shfl_down(s, o);
    __shared__ float red[4];
    if ((t & 63) == 0) red[t >> 6] = s;
    __syncthreads();
    if (t == 0) atomicAdd(out, red[0] + red[1] + red[2] + red[3]);
}

// ---------------------------------------------------------------------------
extern "C" void kernel_launch(void* const* d_in, const int* in_sizes, int n_in,
                              void* d_out, int out_size, void* d_ws, size_t ws_size,
                              hipStream_t stream) {
    const float* z1 = (const float*)d_in[0];
    const float* z2 = (const float*)d_in[1];
    const float* p1 = (const float*)d_in[2];
    const float* p2 = (const float*)d_in[3];
    const float* W1 = (const float*)d_in[4];
    const float* gamma = (const float*)d_in[5];
    const float* beta = (const float*)d_in[6];
    const float* W2 = (const float*)d_in[7];
    const float* b2 = (const float*)d_in[8];
    const float* lam = (const float*)d_in[9];
    float* out = (float*)d_out;
    char* ws = (char*)d_ws;

    // workspace layout (~93 MB)
    size_t off = 0;
    auto alloc = [&](size_t bytes) { size_t o = off; off += (bytes + 255) & ~(size_t)255; return o; };
    unsigned short* W1T = (unsigned short*)(ws + alloc((size_t)E_DIM * H_DIM * 2));  // [H,E] bf16
    unsigned short* W2T = (unsigned short*)(ws + alloc((size_t)H_DIM * E_DIM * 2));  // [E,H] bf16
    unsigned short* zb1 = (unsigned short*)(ws + alloc((size_t)B_ROWS * E_DIM * 2));
    unsigned short* zb2 = (unsigned short*)(ws + alloc((size_t)B_ROWS * E_DIM * 2));
    unsigned short* h   = (unsigned short*)(ws + alloc((size_t)B_ROWS * H_DIM * 2));
    // q1,q2,Ma,Mb contiguous -> single memset
    float* q1 = (float*)(ws + alloc((size_t)B_ROWS * E_DIM * 4));
    float* q2 = (float*)(ws + alloc((size_t)B_ROWS * E_DIM * 4));
    float* Ma  = (float*)(ws + alloc((size_t)E_DIM * E_DIM * 4));
    float* Mb  = (float*)(ws + alloc((size_t)E_DIM * E_DIM * 4));
    float* M2a = (float*)(ws + alloc((size_t)E_DIM * E_DIM * 4));
    float* M2b = (float*)(ws + alloc((size_t)E_DIM * E_DIM * 4));
    // two colsum sets (one per view), contiguous -> single memset
    float* cs0 = (float*)(ws + alloc(H_DIM * 4));
    float* cs0q = (float*)(ws + alloc(H_DIM * 4));
    float* cs1 = (float*)(ws + alloc(H_DIM * 4));
    float* cs1q = (float*)(ws + alloc(H_DIM * 4));
    unsigned* ssb = (unsigned*)(ws + alloc(H_DIM * 4));

    // transposed normalized bf16 views alias into h (free after last GEMM2)
    const size_t TSZ = (size_t)E_DIM * B_ROWS;  // 2M elements each
    unsigned short* p1T = h;
    unsigned short* q2T = h + TSZ;
    unsigned short* p2T = h + 2 * TSZ;
    unsigned short* q1T = h + 3 * TSZ;

    // zero accumulation targets (3 memsets total)
    hipMemsetAsync(out, 0, sizeof(float), stream);
    hipMemsetAsync(q1, 0, ((size_t)2 * B_ROWS * E_DIM + 2 * E_DIM * E_DIM) * 4, stream);
    hipMemsetAsync(cs0, 0, (size_t)4 * H_DIM * 4, stream);

    // fused weight transposes + fused view casts (-2 launches, proven R23)
    k_transpose_cast2<<<dim3(2048), 256, 0, stream>>>(W1, W1T, W2, W2T);
    k_cast2<<<dim3(B_ROWS * E_DIM / 4 / 256, 2), 256, 0, stream>>>(z1, zb1, z2, zb2);

    const unsigned short* zbs[2] = {zb1, zb2};
    float* qs[2] = {q1, q2};
    float* css[2] = {cs0, cs1};
    float* cssq[2] = {cs0q, cs1q};
    for (int v = 0; v < 2; ++v) {
        // h = z @ W1, with fused column stats — BK=32 reg-staged, single barrier
        k_gemm1<<<dim3(H_DIM / 128, B_ROWS / 128), 256, 0, stream>>>(
            zbs[v], W1T, h, css[v], cssq[v], B_ROWS, H_DIM, E_DIM);
        k_bnprep<<<dim3(H_DIM / 256), 256, 0, stream>>>(css[v], cssq[v], gamma, beta, ssb);
        // q = relu(bn(h)) @ W2 + b2 — BK=64, XCD-pair swizzle, split-K x2
        k_gemm2d<<<dim3(1024), 256, 0, stream>>>(
            h, W2T, qs[v], b2, ssb, B_ROWS, E_DIM, H_DIM);
    }

    // fused row-norm + transpose + cast of p1,q2,p2,q1 (into h's space)
    k_ntc<<<dim3(B_ROWS / 32, 4), 256, 0, stream>>>(
        p1, q2, p2, q1, p1T, q2T, p2T, q1T);

    k_gram<<<dim3(4, 4, 2 * GKS), 256, 0, stream>>>(p1T, q2T, p2T, q1T, Ma, Mb);
    k_m2<<<dim3(16, 16, 2), 256, 0, stream>>>(Ma, Mb, M2a, M2b);
    k_traces2<<<dim3(8, 8, 2), 256, 0, stream>>>(Ma, M2a, Mb, M2b, lam, out);
}

// Round 15
// 301.726 us; speedup vs baseline: 1.3271x; 1.0149x over previous
//
#include <hip/hip_runtime.h>

// Problem constants (fixed by reference)
#define B_ROWS 8192
#define E_DIM  256
#define H_DIM  4096

typedef __attribute__((ext_vector_type(8))) short short8;
typedef __attribute__((ext_vector_type(4))) float f32x4;

typedef __attribute__((address_space(1))) const void* gas1_t;
typedef __attribute__((address_space(3))) void*       las3_t;

__device__ __forceinline__ float b2f(unsigned short s) {
    return __uint_as_float(((unsigned)s) << 16);
}
__device__ __forceinline__ unsigned short f2b(float f) {
    unsigned u = __float_as_uint(f);
    u += 0x7fffu + ((u >> 16) & 1u);   // RNE
    return (unsigned short)(u >> 16);
}

// HW packed f32->bf16 convert (1 instr for 2 elems vs 4 VALU ops each).
// GEMM2 A-path only; absmax bit-identical (7.63e-6) across R16-R29.
__device__ __forceinline__ unsigned cvt_pk_bf16(float lo, float hi) {
    unsigned r;
    asm("v_cvt_pk_bf16_f32 %0, %1, %2" : "=v"(r) : "v"(lo), "v"(hi));
    return r;
}

// LDS-only barrier: waits lgkmcnt(0) but does NOT drain vmcnt -- prefetched
// global loads stay in flight across the barrier (R21, proven across 9 rounds).
__device__ __forceinline__ void lds_barrier() {
    asm volatile("s_waitcnt lgkmcnt(0)\n\ts_barrier" ::: "memory");
}

// LDS swizzle for BK=32 (64B rows, 4x16B slots): slot' = slot ^ ((row>>1)&3)
__device__ __forceinline__ int swz(int row, int slot) {
    return slot ^ ((row >> 1) & 3);
}

// ---------------------------------------------------------------------------
// Fused transpose+cast for BOTH weights in one launch (correctness-proven R23).
// blocks 0..1023: W1 [E,H] -> W1T; blocks 1024..2047: W2 [H,E] -> W2T.
__global__ void k_transpose_cast2(const float* __restrict__ W1,
                                  unsigned short* __restrict__ W1T,
                                  const float* __restrict__ W2,
                                  unsigned short* __restrict__ W2T) {
    const int bid = blockIdx.x;
    const int m = bid >> 10, b = bid & 1023;
    const float* in; unsigned short* out; int R, C, cx, cy;
    if (m == 0) { in = W1; out = W1T; R = E_DIM; C = H_DIM; cx = b & 127; cy = b >> 7; }
    else        { in = W2; out = W2T; R = H_DIM; C = E_DIM; cx = b & 7;   cy = b >> 3; }
    const int c0 = cx * 32, r0 = cy * 32;

    __shared__ float tile[32][33];
    const int tx = threadIdx.x & 31, ty = threadIdx.x >> 5;  // ty 0..7
#pragma unroll
    for (int j = 0; j < 4; ++j)
        tile[ty * 4 + j][tx] = in[(size_t)(r0 + ty * 4 + j) * C + c0 + tx];
    __syncthreads();
#pragma unroll
    for (int j = 0; j < 4; ++j)
        out[(size_t)(c0 + ty * 4 + j) * R + r0 + tx] = f2b(tile[tx][ty * 4 + j]);
}

// ---------------------------------------------------------------------------
// Cast f32 -> bf16 for BOTH views in one launch (correctness-proven R23).
__global__ void k_cast2(const float* __restrict__ z1, unsigned short* __restrict__ o1,
                        const float* __restrict__ z2, unsigned short* __restrict__ o2) {
    const float* in = blockIdx.y ? z2 : z1;
    unsigned short* out = blockIdx.y ? o2 : o1;
    int i = blockIdx.x * blockDim.x + threadIdx.x;
    float4 v = ((const float4*)in)[i];
    ushort4 o;
    o.x = f2b(v.x); o.y = f2b(v.y); o.z = f2b(v.z); o.w = f2b(v.w);
    ((ushort4*)out)[i] = o;
}

// ---------------------------------------------------------------------------
// GEMM1 (R26 lineage, restored verbatim — best-measured-total config):
// h = A*Bt^T bf16 + fused col stats. BM=BN=128, BK=32, swizzled
// global_load_lds staging. grid (N/128, M/128). R27/R29 reg-staged variants
// were kernel-faster but total-neutral (contention redistribution).
__global__ __launch_bounds__(256) void k_gemm1(
    const unsigned short* __restrict__ A, const unsigned short* __restrict__ Bt,
    unsigned short* __restrict__ Cout,
    float* __restrict__ cs, float* __restrict__ cs2,
    int M, int N, int K) {
    constexpr int BK = 32, BM = 128, BN = 128;
    constexpr int MI = 4, NI = 4;
    __shared__ __align__(16) short As[BM * BK];
    __shared__ __align__(16) short Bs[BN * BK];

    const int t = threadIdx.x;
    const int lane = t & 63, wv = t >> 6;
    const int wr = wv >> 1, wc = wv & 1;
    const int l15 = lane & 15, quad = lane >> 4;
    const int m0 = blockIdx.y * BM, n0 = blockIdx.x * BN;

    f32x4 acc[MI][NI] = {};

    for (int k0 = 0; k0 < K; k0 += BK) {
#pragma unroll
        for (int q = 0; q < 2; ++q) {
            int u = q * 256 + t;
            int row = u >> 2, kc = swz(row, u & 3);
            const short* gp = (const short*)A + (size_t)(m0 + row) * K + k0 + kc * 8;
            short* lp = As + (size_t)(q * 256 + (wv << 6)) * 8;  // wave-uniform base
            __builtin_amdgcn_global_load_lds((gas1_t)gp, (las3_t)lp, 16, 0, 0);
        }
#pragma unroll
        for (int q = 0; q < 2; ++q) {
            int u = q * 256 + t;
            int row = u >> 2, kc = swz(row, u & 3);
            const short* gp = (const short*)Bt + (size_t)(n0 + row) * K + k0 + kc * 8;
            short* lp = Bs + (size_t)(q * 256 + (wv << 6)) * 8;
            __builtin_amdgcn_global_load_lds((gas1_t)gp, (las3_t)lp, 16, 0, 0);
        }
        __syncthreads();

        short8 af[MI], bfr[NI];
#pragma unroll
        for (int mi = 0; mi < MI; ++mi) {
            int row = wr * 64 + mi * 16 + l15;
            af[mi] = *(const short8*)(As + row * BK + (swz(row, quad) << 3));
        }
#pragma unroll
        for (int ni = 0; ni < NI; ++ni) {
            int row = wc * 64 + ni * 16 + l15;
            bfr[ni] = *(const short8*)(Bs + row * BK + (swz(row, quad) << 3));
        }
#pragma unroll
        for (int mi = 0; mi < MI; ++mi)
#pragma unroll
            for (int ni = 0; ni < NI; ++ni)
                acc[mi][ni] = __builtin_amdgcn_mfma_f32_16x16x32_bf16(
                    af[mi], bfr[ni], acc[mi][ni], 0, 0, 0);
        __syncthreads();
    }

    // epilogue: C/D layout col=lane&15, row=quad*4+reg (measured m89)
#pragma unroll
    for (int ni = 0; ni < NI; ++ni) {
        float s = 0.f, s2 = 0.f;
#pragma unroll
        for (int mi = 0; mi < MI; ++mi)
#pragma unroll
            for (int r = 0; r < 4; ++r) {
                int row = m0 + wr * 64 + mi * 16 + quad * 4 + r;
                int col = n0 + wc * 64 + ni * 16 + l15;
                float v = acc[mi][ni][r];
                Cout[(size_t)row * N + col] = f2b(v);
                s += v; s2 += v * v;
            }
        s  += __shfl_xor(s, 16);  s  += __shfl_xor(s, 32);
        s2 += __shfl_xor(s2, 16); s2 += __shfl_xor(s2, 32);
        if (quad == 0) {
            int col = n0 + wc * 64 + ni * 16 + l15;
            atomicAdd(&cs[col], s);
            atomicAdd(&cs2[col], s2);
        }
    }
}

// BN scale/shift packed as bf16 pair: ssb[k] = f2b(scale)<<16 | f2b(shift)
__global__ void k_bnprep(const float* __restrict__ sum, const float* __restrict__ sumsq,
                         const float* __restrict__ gamma, const float* __restrict__ beta,
                         unsigned* __restrict__ ssb) {
    int j = blockIdx.x * 256 + threadIdx.x;
    float mu = sum[j] * (1.f / B_ROWS);
    float var = sumsq[j] * (1.f / B_ROWS) - mu * mu;
    float sc = gamma[j] * rsqrtf(var + 1e-5f);
    float sh = beta[j] - mu * sc;
    ssb[j] = ((unsigned)f2b(sc) << 16) | (unsigned)f2b(sh);
}

__device__ __forceinline__ short8 bnrelu8(uint4 hv, uint4 sa, uint4 sb) {
    const unsigned short* hu = (const unsigned short*)&hv;
    const unsigned* wa = (const unsigned*)&sa;
    const unsigned* wb = (const unsigned*)&sb;
    float f[8];
#pragma unroll
    for (int j = 0; j < 8; ++j) {
        unsigned w = j < 4 ? wa[j] : wb[j - 4];
        float sc = __uint_as_float(w & 0xffff0000u);
        float sh = __uint_as_float(w << 16);
        f[j] = fmaxf(b2f(hu[j]) * sc + sh, 0.f);
    }
    union { unsigned u[4]; short8 s; } o;
#pragma unroll
    for (int j = 0; j < 4; ++j) o.u[j] = cvt_pk_bf16(f[2 * j], f[2 * j + 1]);
    return o.s;
}

// ---------------------------------------------------------------------------
// GEMM2 (R26, frozen): BK=64, XCD-pair swizzle, lgkm-only barrier, split-K x2.
__global__ __launch_bounds__(256, 4) void k_gemm2d(
    const unsigned short* __restrict__ A, const unsigned short* __restrict__ Bt,
    float* __restrict__ Cout, const float* __restrict__ bias,
    const unsigned* __restrict__ ssb,
    int M, int N, int K) {
    constexpr int BK = 64, BM = 32, BN = 128;
    constexpr int NI = 4;
    __shared__ __align__(16) short As[2][BM * BK];   // 2 x 4 KB
    __shared__ __align__(16) short Bs[2][BN * BK];   // 2 x 16 KB

    const int t = threadIdx.x;
    const int lane = t & 63, wv = t >> 6;
    const int wr = wv >> 1, wc = wv & 1;             // 2x2 wave grid, tile 16x64
    const int l15 = lane & 15, quad = lane >> 4;

    // XCD-pair swizzle decode (grid = 1024 x 1 x 1, split-K x2) -- R25 proven
    const int bid = blockIdx.x;
    const int xcd = bid & 7, sl = bid >> 3;
    const int xp = sl & 1, pidx = (sl >> 1) * 8 + xcd;   // 0..511
    const int m0 = (pidx & 255) * BM;                     // 256 m-blocks
    const int n0 = xp * BN;                               // 2 n-blocks
    const int bz = pidx >> 8;                             // 2 k-chunks

    const int Kc = K >> 1;                                // split-K x2
    const int kbeg = bz * Kc;
    const int ITERS = Kc / BK;                            // 32

    // A staging: all 256 threads, row = t>>3 (0..31), kslot = t&7 (8x16B/row)
    const int arow = t >> 3, aks = t & 7;
    const unsigned short* hp = A + (size_t)(m0 + arow) * K + aks * 8;
    const unsigned* ssp = ssb + aks * 8;
    const int aswz = (aks ^ (arow & 7)) << 3;             // (32j)&7==0 -> row-invariant
    const int awoff = arow * BK + aswz;

    // B staging: 4 row-chunks arow+32j at the same kslot
    const unsigned short* bp0 = Bt + (size_t)(n0 + arow) * K + aks * 8;
    const int bwoff0 = arow * BK + aswz;                  // + 32j*BK for j=1..3

    f32x4 acc[NI] = {};

    uint4 hreg = *(const uint4*)(hp + kbeg);
    uint4 sa = *(const uint4*)(ssp + kbeg);
    uint4 sb = *(const uint4*)(ssp + kbeg + 4);
    uint4 b0 = *(const uint4*)(bp0 + kbeg);
    uint4 b1 = *(const uint4*)(bp0 + (size_t)32 * K + kbeg);
    uint4 b2r = *(const uint4*)(bp0 + (size_t)64 * K + kbeg);
    uint4 b3 = *(const uint4*)(bp0 + (size_t)96 * K + kbeg);

    for (int i = 0; i < ITERS; ++i) {
        const int k0 = kbeg + i * BK;
        short* Ab = As[i & 1];
        short* Bb = Bs[i & 1];

        *(short8*)(Ab + awoff) = bnrelu8(hreg, sa, sb);
        *(uint4*)(Bb + bwoff0)           = b0;
        *(uint4*)(Bb + bwoff0 + 32 * BK) = b1;
        *(uint4*)(Bb + bwoff0 + 64 * BK) = b2r;
        *(uint4*)(Bb + bwoff0 + 96 * BK) = b3;
        lds_barrier();   // lgkm-only: prefetch loads stay in flight

        const int kn = (i + 1 < ITERS) ? k0 + BK : kbeg;
        hreg = *(const uint4*)(hp + kn);
        sa = *(const uint4*)(ssp + kn);
        sb = *(const uint4*)(ssp + kn + 4);
        b0 = *(const uint4*)(bp0 + kn);
        b1 = *(const uint4*)(bp0 + (size_t)32 * K + kn);
        b2r = *(const uint4*)(bp0 + (size_t)64 * K + kn);
        b3 = *(const uint4*)(bp0 + (size_t)96 * K + kn);

        // fragments: 2 k-halves (kk=0: slots quad; kk=1: slots 4+quad)
        short8 af[2], bfr[2][NI];
        {
            int row = wr * 16 + l15;
            af[0] = *(const short8*)(Ab + row * BK + (((quad)     ^ (row & 7)) << 3));
            af[1] = *(const short8*)(Ab + row * BK + (((4 + quad) ^ (row & 7)) << 3));
        }
#pragma unroll
        for (int ni = 0; ni < NI; ++ni) {
            int row = wc * 64 + ni * 16 + l15;
            bfr[0][ni] = *(const short8*)(Bb + row * BK + (((quad)     ^ (row & 7)) << 3));
            bfr[1][ni] = *(const short8*)(Bb + row * BK + (((4 + quad) ^ (row & 7)) << 3));
        }
#pragma unroll
        for (int kk = 0; kk < 2; ++kk)
#pragma unroll
            for (int ni = 0; ni < NI; ++ni)
                acc[ni] = __builtin_amdgcn_mfma_f32_16x16x32_bf16(
                    af[kk], bfr[kk][ni], acc[ni], 0, 0, 0);
    }

#pragma unroll
    for (int ni = 0; ni < NI; ++ni)
#pragma unroll
        for (int r = 0; r < 4; ++r) {
            int row = m0 + wr * 16 + quad * 4 + r;
            int col = n0 + wc * 64 + ni * 16 + l15;
            float v = acc[ni][r];
            if (bz == 0) v += bias[col];
            atomicAdd(&Cout[(size_t)row * N + col], v);
        }
}

// ---------------------------------------------------------------------------
// Fused norm + transpose + cast (R14-proven): grid (B/32, 4), block 256.
__global__ __launch_bounds__(256) void k_ntc(
    const float* __restrict__ x0, const float* __restrict__ x1,
    const float* __restrict__ x2, const float* __restrict__ x3,
    unsigned short* __restrict__ o0, unsigned short* __restrict__ o1,
    unsigned short* __restrict__ o2, unsigned short* __restrict__ o3) {
    const int z = blockIdx.y;
    const float* x = z == 0 ? x0 : z == 1 ? x1 : z == 2 ? x2 : x3;
    unsigned short* out = z == 0 ? o0 : z == 1 ? o1 : z == 2 ? o2 : o3;

    __shared__ float tile[32][264];
    __shared__ float red[32][8];
    __shared__ float invs[32];
    const int t = threadIdx.x;
    const int r0 = blockIdx.x * 32;

#pragma unroll
    for (int i = 0; i < 8; ++i) {
        int u = i * 256 + t;
        int row = u >> 6, cp = (u & 63) * 4;
        float4 v = *(const float4*)(x + (size_t)(r0 + row) * E_DIM + cp);
        *(float4*)&tile[row][cp] = v;
    }
    __syncthreads();
    {
        int row = t >> 3, cg = (t & 7) * 32;
        float s = 0.f;
#pragma unroll
        for (int j = 0; j < 32; ++j) { float v = tile[row][cg + j]; s += v * v; }
        red[row][t & 7] = s;
    }
    __syncthreads();
    if (t < 32) {
        float s = 0.f;
#pragma unroll
        for (int j = 0; j < 8; ++j) s += red[t][j];
        invs[t] = 1.f / fmaxf(sqrtf(s), 1e-12f);
    }
    __syncthreads();
    {
        int row = t & 31, cb = (t >> 5) * 32;
        float inv = invs[row];
#pragma unroll
        for (int j = 0; j < 32; ++j) {
            int c = cb + j;
            out[(size_t)c * B_ROWS + r0 + row] = f2b(tile[row][c] * inv);
        }
    }
}

// ---------------------------------------------------------------------------
// Gram via MFMA (R30): ported to the PROVEN reg-staged single-lgkm-barrier
// structure (gemm2d since R21). Old version had 2 vmcnt-draining
// __syncthreads per K-iter x 16 iters with only 4 MFMA between -- the same
// serial-latency disease measured in gemm1/gemm2d. Each thread stages
// 1 A + 1 B uint4 (row=t>>2, slot=t&3, proven BK=32 swizzle), double-buffered
// 16 KB LDS, 1-deep prefetch. Grid/epilogue/math unchanged: (4,4,32).
#define GKS 16
__global__ __launch_bounds__(256) void k_gram(
    const unsigned short* __restrict__ p1T, const unsigned short* __restrict__ q2T,
    const unsigned short* __restrict__ p2T, const unsigned short* __restrict__ q1T,
    float* __restrict__ Ma, float* __restrict__ Mb) {
    constexpr int BK = 32;
    const int mec = blockIdx.z >> 4, kz = blockIdx.z & 15;
    const unsigned short* A = mec ? p2T : p1T;
    const unsigned short* Bt = mec ? q1T : q2T;
    float* Mout = mec ? Mb : Ma;

    __shared__ __align__(16) short As[2][64 * BK];   // 2 x 4 KB
    __shared__ __align__(16) short Bs[2][64 * BK];   // 2 x 4 KB

    const int t = threadIdx.x;
    const int lane = t & 63, wv = t >> 6;
    const int wr = wv >> 1, wc = wv & 1;
    const int l15 = lane & 15, quad = lane >> 4;
    const int m0 = blockIdx.y * 64, n0 = blockIdx.x * 64;
    const int kbeg = kz * (B_ROWS / GKS);
    const int ITERS = (B_ROWS / GKS) / BK;   // 16

    // staging: row = t>>2 (0..63), slot = t&3 (4x16B slots/row)
    const int r0s = t >> 2, sl = t & 3;
    const unsigned short* ap = A + (size_t)(m0 + r0s) * B_ROWS + sl * 8;
    const unsigned short* bp = Bt + (size_t)(n0 + r0s) * B_ROWS + sl * 8;
    const int awo = r0s * BK + (swz(r0s, sl) << 3);

    f32x4 acc[2][2] = {};

    uint4 a0 = *(const uint4*)(ap + kbeg);
    uint4 b0 = *(const uint4*)(bp + kbeg);

    for (int i = 0; i < ITERS; ++i) {
        short* Ab = As[i & 1];
        short* Bb = Bs[i & 1];

        *(uint4*)(Ab + awo) = a0;
        *(uint4*)(Bb + awo) = b0;
        lds_barrier();   // lgkm-only: prefetch loads stay in flight

        const int kn = kbeg + ((i + 1 < ITERS) ? (i + 1) * BK : 0);
        a0 = *(const uint4*)(ap + kn);
        b0 = *(const uint4*)(bp + kn);

        short8 af[2], bfr[2];
#pragma unroll
        for (int mi = 0; mi < 2; ++mi) {
            int row = wr * 32 + mi * 16 + l15;
            af[mi] = *(const short8*)(Ab + row * BK + (swz(row, quad) << 3));
        }
#pragma unroll
        for (int ni = 0; ni < 2; ++ni) {
            int row = wc * 32 + ni * 16 + l15;
            bfr[ni] = *(const short8*)(Bb + row * BK + (swz(row, quad) << 3));
        }
#pragma unroll
        for (int mi = 0; mi < 2; ++mi)
#pragma unroll
            for (int ni = 0; ni < 2; ++ni)
                acc[mi][ni] = __builtin_amdgcn_mfma_f32_16x16x32_bf16(
                    af[mi], bfr[ni], acc[mi][ni], 0, 0, 0);
    }

#pragma unroll
    for (int mi = 0; mi < 2; ++mi)
#pragma unroll
        for (int ni = 0; ni < 2; ++ni)
#pragma unroll
            for (int r = 0; r < 4; ++r) {
                int row = m0 + wr * 32 + mi * 16 + quad * 4 + r;
                int col = n0 + wc * 32 + ni * 16 + l15;
                atomicAdd(&Mout[(size_t)row * E_DIM + col], acc[mi][ni][r]);
            }
}

// M2 = M*M (256x256). grid (16,16,2) block 256. (R21 state)
__global__ void k_m2(const float* __restrict__ Ma, const float* __restrict__ Mb,
                     float* __restrict__ M2a, float* __restrict__ M2b) {
    const float* M = blockIdx.z ? Mb : Ma;
    float* M2 = blockIdx.z ? M2b : M2a;
    int b = blockIdx.x * 16 + (threadIdx.x & 15);
    int a = blockIdx.y * 16 + (threadIdx.x >> 4);
    float s = 0.f;
    for (int k = 0; k < E_DIM; ++k) s += M[a * E_DIM + k] * M[k * E_DIM + b];
    M2[a * E_DIM + b] = s;
}

// ---------------------------------------------------------------------------
// Traces, tiled multi-block: grid (8,8,2), block 256.
__global__ __launch_bounds__(256) void k_traces2(
    const float* __restrict__ Ma, const float* __restrict__ M2a,
    const float* __restrict__ Mb, const float* __restrict__ M2b,
    const float* __restrict__ lam, float* __restrict__ out) {
    const float* M  = blockIdx.z ? Mb  : Ma;
    const float* M2 = blockIdx.z ? M2b : M2a;
    const int i0 = blockIdx.y * 32, j0 = blockIdx.x * 32;
    const int t = threadIdx.x, col = t & 31, row = t >> 5;  // row 0..7

    __shared__ float A[32][33], Bt[32][33], A2[32][33], B2[32][33];
#pragma unroll
    for (int r = 0; r < 4; ++r) {
        int rr = r * 8 + row;
        A [rr][col] = M [(i0 + rr) * E_DIM + j0 + col];
        Bt[rr][col] = M [(j0 + rr) * E_DIM + i0 + col];
        A2[rr][col] = M2[(i0 + rr) * E_DIM + j0 + col];
        B2[rr][col] = M2[(j0 + rr) * E_DIM + i0 + col];
    }
    __syncthreads();

    float lamv = lam[0];
    float il = 1.f / lamv;
    float F = -0.5f * lamv * (1.f / B_ROWS);  // -0.5*lam/B
    float c1 = F * il;
    float c2 = -F * 0.5f * il * il;
    float c3 = F * (1.f / 3.f) * il * il * il;
    float c4 = -F * 0.25f * il * il * il * il;

    float s = 0.f;
#pragma unroll
    for (int r = 0; r < 4; ++r) {
        int rr = r * 8 + row;
        float mij = A[rr][col], mji = Bt[col][rr];
        float m2ij = A2[rr][col], m2ji = B2[col][rr];
        s += c2 * mij * mji + c3 * m2ij * mji + c4 * m2ij * m2ji;
        if (i0 + rr == j0 + col) s += c1 * mij;
    }
#pragma unroll
    for (int o = 32; o; o >>= 1) s += __shfl_down(s, o);
    __shared__ float red[4];
    if ((t & 63) == 0) red[t >> 6] = s;
    __syncthreads();
    if (t == 0) atomicAdd(out, red[0] + red[1] + red[2] + red[3]);
}

// ---------------------------------------------------------------------------
extern "C" void kernel_launch(void* const* d_in, const int* in_sizes, int n_in,
                              void* d_out, int out_size, void* d_ws, size_t ws_size,
                              hipStream_t stream) {
    const float* z1 = (const float*)d_in[0];
    const float* z2 = (const float*)d_in[1];
    const float* p1 = (const float*)d_in[2];
    const float* p2 = (const float*)d_in[3];
    const float* W1 = (const float*)d_in[4];
    const float* gamma = (const float*)d_in[5];
    const float* beta = (const float*)d_in[6];
    const float* W2 = (const float*)d_in[7];
    const float* b2 = (const float*)d_in[8];
    const float* lam = (const float*)d_in[9];
    float* out = (float*)d_out;
    char* ws = (char*)d_ws;

    // workspace layout (~93 MB)
    size_t off = 0;
    auto alloc = [&](size_t bytes) { size_t o = off; off += (bytes + 255) & ~(size_t)255; return o; };
    unsigned short* W1T = (unsigned short*)(ws + alloc((size_t)E_DIM * H_DIM * 2));  // [H,E] bf16
    unsigned short* W2T = (unsigned short*)(ws + alloc((size_t)H_DIM * E_DIM * 2));  // [E,H] bf16
    unsigned short* zb1 = (unsigned short*)(ws + alloc((size_t)B_ROWS * E_DIM * 2));
    unsigned short* zb2 = (unsigned short*)(ws + alloc((size_t)B_ROWS * E_DIM * 2));
    unsigned short* h   = (unsigned short*)(ws + alloc((size_t)B_ROWS * H_DIM * 2));
    // q1,q2,Ma,Mb contiguous -> single memset
    float* q1 = (float*)(ws + alloc((size_t)B_ROWS * E_DIM * 4));
    float* q2 = (float*)(ws + alloc((size_t)B_ROWS * E_DIM * 4));
    float* Ma  = (float*)(ws + alloc((size_t)E_DIM * E_DIM * 4));
    float* Mb  = (float*)(ws + alloc((size_t)E_DIM * E_DIM * 4));
    float* M2a = (float*)(ws + alloc((size_t)E_DIM * E_DIM * 4));
    float* M2b = (float*)(ws + alloc((size_t)E_DIM * E_DIM * 4));
    // two colsum sets (one per view), contiguous -> single memset
    float* cs0 = (float*)(ws + alloc(H_DIM * 4));
    float* cs0q = (float*)(ws + alloc(H_DIM * 4));
    float* cs1 = (float*)(ws + alloc(H_DIM * 4));
    float* cs1q = (float*)(ws + alloc(H_DIM * 4));
    unsigned* ssb = (unsigned*)(ws + alloc(H_DIM * 4));

    // transposed normalized bf16 views alias into h (free after last GEMM2)
    const size_t TSZ = (size_t)E_DIM * B_ROWS;  // 2M elements each
    unsigned short* p1T = h;
    unsigned short* q2T = h + TSZ;
    unsigned short* p2T = h + 2 * TSZ;
    unsigned short* q1T = h + 3 * TSZ;

    // zero accumulation targets (3 memsets total)
    hipMemsetAsync(out, 0, sizeof(float), stream);
    hipMemsetAsync(q1, 0, ((size_t)2 * B_ROWS * E_DIM + 2 * E_DIM * E_DIM) * 4, stream);
    hipMemsetAsync(cs0, 0, (size_t)4 * H_DIM * 4, stream);

    // fused weight transposes + fused view casts (-2 launches, proven R23)
    k_transpose_cast2<<<dim3(2048), 256, 0, stream>>>(W1, W1T, W2, W2T);
    k_cast2<<<dim3(B_ROWS * E_DIM / 4 / 256, 2), 256, 0, stream>>>(z1, zb1, z2, zb2);

    const unsigned short* zbs[2] = {zb1, zb2};
    float* qs[2] = {q1, q2};
    float* css[2] = {cs0, cs1};
    float* cssq[2] = {cs0q, cs1q};
    for (int v = 0; v < 2; ++v) {
        // h = z @ W1, with fused column stats (R26 lineage)
        k_gemm1<<<dim3(H_DIM / 128, B_ROWS / 128), 256, 0, stream>>>(
            zbs[v], W1T, h, css[v], cssq[v], B_ROWS, H_DIM, E_DIM);
        k_bnprep<<<dim3(H_DIM / 256), 256, 0, stream>>>(css[v], cssq[v], gamma, beta, ssb);
        // q = relu(bn(h)) @ W2 + b2 — BK=64, XCD-pair swizzle, split-K x2
        k_gemm2d<<<dim3(1024), 256, 0, stream>>>(
            h, W2T, qs[v], b2, ssb, B_ROWS, E_DIM, H_DIM);
    }

    // fused row-norm + transpose + cast of p1,q2,p2,q1 (into h's space)
    k_ntc<<<dim3(B_ROWS / 32, 4), 256, 0, stream>>>(
        p1, q2, p2, q1, p1T, q2T, p2T, q1T);

    k_gram<<<dim3(4, 4, 2 * GKS), 256, 0, stream>>>(p1T, q2T, p2T, q1T, Ma, Mb);
    k_m2<<<dim3(16, 16, 2), 256, 0, stream>>>(Ma, Mb, M2a, M2b);
    k_traces2<<<dim3(8, 8, 2), 256, 0, stream>>>(Ma, M2a, Mb, M2b, lam, out);
}